// Round 12
// baseline (191.628 us; speedup 1.0000x reference)
//
#include <hip/hip_runtime.h>

#define DIM 128
#define NUM_OUT 100000
#define N_SRC 200000
#define OFFS_BYTES (((4 * (NUM_OUT + 1)) + 511) / 512 * 512)

typedef float v2f __attribute__((ext_vector_type(2)));
typedef float v4f __attribute__((ext_vector_type(4)));
typedef float f32x4 __attribute__((ext_vector_type(4)));
typedef _Float16 f16x2 __attribute__((ext_vector_type(2)));
typedef _Float16 f16x4 __attribute__((ext_vector_type(4)));
typedef _Float16 f16x8 __attribute__((ext_vector_type(8)));

__device__ __forceinline__ float fast_tanh(float x) {
  const float xc = fminf(fmaxf(x, -15.f), 15.f);
  const float t = __expf(2.f * xc);
  return __fdividef(t - 1.f, t + 1.f);
}

// Kernel 0: segment boundaries. offs[s] = first edge e with seg[e] >= s.
__global__ __launch_bounds__(256) void build_offs(
    const int* __restrict__ seg, int* __restrict__ offs, int n_edges, int n_out) {
  const int e = blockIdx.x * 256 + threadIdx.x;
  if (e >= n_edges) return;
  const int se = seg[e];
  const int sp = (e == 0) ? -1 : seg[e - 1];
  for (int s = sp + 1; s <= se; ++s) offs[s] = e;
  if (e == n_edges - 1) {
    for (int s = se + 1; s <= n_out; ++s) offs[s] = n_edges;
  }
}

// Kernel 1: z = values @ W in fp16 (f32 accum), z stored fp16 [N_SRC,128].
// 256 threads = 4 waves, 64 rows/block. x and W^T staged in LDS as fp16;
// mfma_f32_16x16x32_f16, fragment layout per m92/m97-verified convention:
//   A: lane row = l&15, 8 contiguous k at (l>>4)*8
//   B: lane col = l&15, 8 contiguous k at (l>>4)*8 (from W^T rows)
//   C/D: col = l&15, row = (l>>4)*4 + reg
__global__ __launch_bounds__(256) void transform_mfma(
    const float* __restrict__ x,
    const float* __restrict__ W,
    _Float16* __restrict__ z) {
  __shared__ _Float16 xL[64 * DIM];    // 16 KB
  __shared__ _Float16 WtL[DIM * DIM];  // 32 KB
  const int tid = threadIdx.x;
  const int m0 = blockIdx.x * 64;

  // stage W^T fp16: read W[k][n] coalesced, write WtL[n][k]
  for (int i = tid; i < DIM * DIM; i += 256) {
    const int k = i >> 7, n = i & 127;
    WtL[n * DIM + k] = (_Float16)W[i];
  }
  // stage x fp16: 64 rows, coalesced v4f reads
  for (int i = tid; i < 64 * 32; i += 256) {
    const int row = i >> 5, c4 = (i & 31) * 4;
    const v4f xv = *(const v4f*)(x + (size_t)(m0 + row) * DIM + c4);
    f16x4 h;
    h.x = (_Float16)xv.x; h.y = (_Float16)xv.y;
    h.z = (_Float16)xv.z; h.w = (_Float16)xv.w;
    *(f16x4*)(&xL[row * DIM + c4]) = h;
  }
  __syncthreads();

  const int w = tid >> 6;
  const int l = tid & 63;
  const int arow = w * 16 + (l & 15);
  const int kblk = (l >> 4) * 8;

  f16x8 af[4];
#pragma unroll
  for (int kb = 0; kb < 4; ++kb)
    af[kb] = *(const f16x8*)(&xL[arow * DIM + kb * 32 + kblk]);

  const int zc_base = l & 15;
  const int zr0 = m0 + w * 16 + (l >> 4) * 4;

#pragma unroll 1
  for (int nt = 0; nt < 8; ++nt) {
    f32x4 acc = {0.f, 0.f, 0.f, 0.f};
#pragma unroll
    for (int kb = 0; kb < 4; ++kb) {
      const f16x8 bf = *(const f16x8*)(&WtL[(nt * 16 + zc_base) * DIM + kb * 32 + kblk]);
      acc = __builtin_amdgcn_mfma_f32_16x16x32_f16(af[kb], bf, acc, 0, 0, 0);
    }
    const int zc = nt * 16 + zc_base;
#pragma unroll
    for (int r = 0; r < 4; ++r)
      z[(size_t)(zr0 + r) * DIM + zc] = (_Float16)acc[r];
  }
}

// Kernel 2: pure gather+segsum+tanh over fp16 z rows (256 B each).
// R3-proven shape: 128 threads = 2 waves = 2 segments/block; 64 lanes x
// 4 B (2 halfs) per row; 8 gathers in flight; f32 accumulation.
__global__ __launch_bounds__(128) void seg_gather_tanh(
    const _Float16* __restrict__ zh,
    const int* __restrict__ gidx,
    const int* __restrict__ offs,
    float* __restrict__ out,
    int n_edges) {
  const int s = blockIdx.x * 2 + (threadIdx.x >> 6);
  const int t = threadIdx.x & 63;

  const int e0 = __builtin_amdgcn_readfirstlane(offs[s]);
  const int e1 = __builtin_amdgcn_readfirstlane(offs[s + 1]);
  const int len = e1 - e0;

  const f16x2* __restrict__ z2 = (const f16x2*)zh;
  float accx = 0.f, accy = 0.f;

  for (int base = 0; base < len; base += 64) {
    const int my = gidx[min(e0 + base + t, n_edges - 1)];
    const int n = min(64, len - base);
    int k = 0;
    for (; k + 8 <= n; k += 8) {
      int r0 = __builtin_amdgcn_readlane(my, k + 0);
      int r1 = __builtin_amdgcn_readlane(my, k + 1);
      int r2 = __builtin_amdgcn_readlane(my, k + 2);
      int r3 = __builtin_amdgcn_readlane(my, k + 3);
      int r4 = __builtin_amdgcn_readlane(my, k + 4);
      int r5 = __builtin_amdgcn_readlane(my, k + 5);
      int r6 = __builtin_amdgcn_readlane(my, k + 6);
      int r7 = __builtin_amdgcn_readlane(my, k + 7);
      const f16x2 a0 = z2[(size_t)r0 * 64 + t];
      const f16x2 a1 = z2[(size_t)r1 * 64 + t];
      const f16x2 a2 = z2[(size_t)r2 * 64 + t];
      const f16x2 a3 = z2[(size_t)r3 * 64 + t];
      const f16x2 a4 = z2[(size_t)r4 * 64 + t];
      const f16x2 a5 = z2[(size_t)r5 * 64 + t];
      const f16x2 a6 = z2[(size_t)r6 * 64 + t];
      const f16x2 a7 = z2[(size_t)r7 * 64 + t];
      accx += (float)a0.x + (float)a1.x + (float)a2.x + (float)a3.x +
              (float)a4.x + (float)a5.x + (float)a6.x + (float)a7.x;
      accy += (float)a0.y + (float)a1.y + (float)a2.y + (float)a3.y +
              (float)a4.y + (float)a5.y + (float)a6.y + (float)a7.y;
    }
    if (k < n) {
      const int nm1 = n - 1;
#pragma unroll
      for (int j = 0; j < 7; j += 4) {
        if (k + j < n) {
          int q0 = __builtin_amdgcn_readlane(my, min(k + j + 0, nm1));
          int q1 = __builtin_amdgcn_readlane(my, min(k + j + 1, nm1));
          int q2 = __builtin_amdgcn_readlane(my, min(k + j + 2, nm1));
          int q3 = __builtin_amdgcn_readlane(my, min(k + j + 3, nm1));
          const float m1 = (k + j + 1 < n) ? 1.f : 0.f;
          const float m2 = (k + j + 2 < n) ? 1.f : 0.f;
          const float m3 = (k + j + 3 < n) ? 1.f : 0.f;
          const f16x2 b0 = z2[(size_t)q0 * 64 + t];
          const f16x2 b1 = z2[(size_t)q1 * 64 + t];
          const f16x2 b2 = z2[(size_t)q2 * 64 + t];
          const f16x2 b3 = z2[(size_t)q3 * 64 + t];
          accx += (float)b0.x + m1 * (float)b1.x + m2 * (float)b2.x + m3 * (float)b3.x;
          accy += (float)b0.y + m1 * (float)b1.y + m2 * (float)b2.y + m3 * (float)b3.y;
        }
      }
    }
  }

  v2f o;
  o.x = fast_tanh(accx);
  o.y = fast_tanh(accy);
  ((v2f*)out)[(size_t)s * 64 + t] = o;
}

extern "C" void kernel_launch(void* const* d_in, const int* in_sizes, int n_in,
                              void* d_out, int out_size, void* d_ws, size_t ws_size,
                              hipStream_t stream) {
  const float* values = (const float*)d_in[0];   // [N_SRC, 128] f32
  const float* W      = (const float*)d_in[1];   // [128, 128] f32
  const int*   gidx   = (const int*)d_in[2];     // [E] int
  const int*   seg    = (const int*)d_in[3];     // [E] int, sorted
  float* out = (float*)d_out;                    // [N_OUT, 128] f32

  int*       offs = (int*)d_ws;                          // [N_OUT+1]
  _Float16*  z    = (_Float16*)((char*)d_ws + OFFS_BYTES);  // [N_SRC,128] fp16, 51.2 MB

  const int n_edges = in_sizes[2];

  build_offs<<<(n_edges + 255) / 256, 256, 0, stream>>>(seg, offs, n_edges, NUM_OUT);
  transform_mfma<<<N_SRC / 64, 256, 0, stream>>>(values, W, z);
  seg_gather_tanh<<<NUM_OUT / 2, 128, 0, stream>>>(z, gidx, offs, out, n_edges);
}

// Round 13
// 137.942 us; speedup vs baseline: 1.3892x; 1.3892x over previous
//
#include <hip/hip_runtime.h>

#define DIM 128
#define NUM_OUT 100000
#define N_SRC 200000
#define OFFS_BYTES (((4 * (NUM_OUT + 1)) + 511) / 512 * 512)
#define WT_BYTES (DIM * DIM * 2)
#define ZT_STRIDE 136  // 16-row LDS out-tile stride in halfs (+8 pad)

typedef float v2f __attribute__((ext_vector_type(2)));
typedef float v4f __attribute__((ext_vector_type(4)));
typedef float f32x4 __attribute__((ext_vector_type(4)));
typedef _Float16 f16x2 __attribute__((ext_vector_type(2)));
typedef _Float16 f16x8 __attribute__((ext_vector_type(8)));

__device__ __forceinline__ float fast_tanh(float x) {
  const float xc = fminf(fmaxf(x, -15.f), 15.f);
  const float t = __expf(2.f * xc);
  return __fdividef(t - 1.f, t + 1.f);
}

// Kernel 0: segment boundaries. offs[s] = first edge e with seg[e] >= s.
__global__ __launch_bounds__(256) void build_offs(
    const int* __restrict__ seg, int* __restrict__ offs, int n_edges, int n_out) {
  const int e = blockIdx.x * 256 + threadIdx.x;
  if (e >= n_edges) return;
  const int se = seg[e];
  const int sp = (e == 0) ? -1 : seg[e - 1];
  for (int s = sp + 1; s <= se; ++s) offs[s] = e;
  if (e == n_edges - 1) {
    for (int s = se + 1; s <= n_out; ++s) offs[s] = n_edges;
  }
}

// Kernel 0b: Wt[n][k] = (fp16) W[k][n]. 16K elements, one-shot.
__global__ __launch_bounds__(256) void wt_fp16(
    const float* __restrict__ W, _Float16* __restrict__ Wt) {
  const int i = blockIdx.x * 256 + threadIdx.x;
  if (i >= DIM * DIM) return;
  const int k = i >> 7, n = i & 127;
  Wt[n * DIM + k] = (_Float16)W[i];
}

// Kernel 1: z = (fp16)(values @ W), f32 accum. 256 thr = 4 waves, 64 rows/blk.
// No LDS on the load path: A-frags cvt'd from global x (coalesced 128B row
// segments), B-frags f16x8 direct from global Wt (L1-hot). Per-wave padded
// LDS tile only to turn the MFMA C-layout into coalesced 16B row writes.
// Fragment layout (R12-validated): A row=l&15, k at (l>>4)*8; B col=l&15;
// C/D col=l&15, row=(l>>4)*4+r.
__global__ __launch_bounds__(256) void transform_mfma(
    const float* __restrict__ x,
    const _Float16* __restrict__ Wt,
    _Float16* __restrict__ z) {
  __shared__ _Float16 zt[4][16 * ZT_STRIDE];  // 17.4 KB

  const int tid = threadIdx.x;
  const int w = tid >> 6;
  const int l = tid & 63;
  const int m0 = blockIdx.x * 64 + w * 16;  // wave's 16 rows

  const int ar = l & 15;
  const int kblk = (l >> 4) * 8;

  f16x8 af[4];
#pragma unroll
  for (int kb = 0; kb < 4; ++kb) {
    const float* p = x + (size_t)(m0 + ar) * DIM + kb * 32 + kblk;
    const v4f x0 = *(const v4f*)(p);
    const v4f x1 = *(const v4f*)(p + 4);
    f16x8 h;
    h[0] = (_Float16)x0.x; h[1] = (_Float16)x0.y;
    h[2] = (_Float16)x0.z; h[3] = (_Float16)x0.w;
    h[4] = (_Float16)x1.x; h[5] = (_Float16)x1.y;
    h[6] = (_Float16)x1.z; h[7] = (_Float16)x1.w;
    af[kb] = h;
  }

  const int cr0 = (l >> 4) * 4;
  const int cc = l & 15;

#pragma unroll 1
  for (int nt = 0; nt < 8; ++nt) {
    f32x4 acc = {0.f, 0.f, 0.f, 0.f};
#pragma unroll
    for (int kb = 0; kb < 4; ++kb) {
      const f16x8 bf = *(const f16x8*)(Wt + (size_t)(nt * 16 + cc) * DIM + kb * 32 + kblk);
      acc = __builtin_amdgcn_mfma_f32_16x16x32_f16(af[kb], bf, acc, 0, 0, 0);
    }
#pragma unroll
    for (int r = 0; r < 4; ++r)
      zt[w][(cr0 + r) * ZT_STRIDE + nt * 16 + cc] = (_Float16)acc[r];
  }

  __syncthreads();

  // coalesced writeback: lane l -> row l>>2, chunks (l&3)+4j (8 halfs each)
  const int row = l >> 2;
#pragma unroll
  for (int j = 0; j < 4; ++j) {
    const int ch = (l & 3) + 4 * j;
    const f16x8 v = *(const f16x8*)(&zt[w][row * ZT_STRIDE + ch * 8]);
    *(f16x8*)(z + (size_t)(m0 + row) * DIM + ch * 8) = v;
  }
}

// Kernel 2: pure gather+segsum+tanh over fp16 z rows (256 B each).
// R3-proven shape (measured ~60 us, bytes-wall limited).
__global__ __launch_bounds__(128) void seg_gather_tanh(
    const _Float16* __restrict__ zh,
    const int* __restrict__ gidx,
    const int* __restrict__ offs,
    float* __restrict__ out,
    int n_edges) {
  const int s = blockIdx.x * 2 + (threadIdx.x >> 6);
  const int t = threadIdx.x & 63;

  const int e0 = __builtin_amdgcn_readfirstlane(offs[s]);
  const int e1 = __builtin_amdgcn_readfirstlane(offs[s + 1]);
  const int len = e1 - e0;

  const f16x2* __restrict__ z2 = (const f16x2*)zh;
  float accx = 0.f, accy = 0.f;

  for (int base = 0; base < len; base += 64) {
    const int my = gidx[min(e0 + base + t, n_edges - 1)];
    const int n = min(64, len - base);
    int k = 0;
    for (; k + 8 <= n; k += 8) {
      int r0 = __builtin_amdgcn_readlane(my, k + 0);
      int r1 = __builtin_amdgcn_readlane(my, k + 1);
      int r2 = __builtin_amdgcn_readlane(my, k + 2);
      int r3 = __builtin_amdgcn_readlane(my, k + 3);
      int r4 = __builtin_amdgcn_readlane(my, k + 4);
      int r5 = __builtin_amdgcn_readlane(my, k + 5);
      int r6 = __builtin_amdgcn_readlane(my, k + 6);
      int r7 = __builtin_amdgcn_readlane(my, k + 7);
      const f16x2 a0 = z2[(size_t)r0 * 64 + t];
      const f16x2 a1 = z2[(size_t)r1 * 64 + t];
      const f16x2 a2 = z2[(size_t)r2 * 64 + t];
      const f16x2 a3 = z2[(size_t)r3 * 64 + t];
      const f16x2 a4 = z2[(size_t)r4 * 64 + t];
      const f16x2 a5 = z2[(size_t)r5 * 64 + t];
      const f16x2 a6 = z2[(size_t)r6 * 64 + t];
      const f16x2 a7 = z2[(size_t)r7 * 64 + t];
      accx += (float)a0.x + (float)a1.x + (float)a2.x + (float)a3.x +
              (float)a4.x + (float)a5.x + (float)a6.x + (float)a7.x;
      accy += (float)a0.y + (float)a1.y + (float)a2.y + (float)a3.y +
              (float)a4.y + (float)a5.y + (float)a6.y + (float)a7.y;
    }
    if (k < n) {
      const int nm1 = n - 1;
#pragma unroll
      for (int j = 0; j < 7; j += 4) {
        if (k + j < n) {
          int q0 = __builtin_amdgcn_readlane(my, min(k + j + 0, nm1));
          int q1 = __builtin_amdgcn_readlane(my, min(k + j + 1, nm1));
          int q2 = __builtin_amdgcn_readlane(my, min(k + j + 2, nm1));
          int q3 = __builtin_amdgcn_readlane(my, min(k + j + 3, nm1));
          const float m1 = (k + j + 1 < n) ? 1.f : 0.f;
          const float m2 = (k + j + 2 < n) ? 1.f : 0.f;
          const float m3 = (k + j + 3 < n) ? 1.f : 0.f;
          const f16x2 b0 = z2[(size_t)q0 * 64 + t];
          const f16x2 b1 = z2[(size_t)q1 * 64 + t];
          const f16x2 b2 = z2[(size_t)q2 * 64 + t];
          const f16x2 b3 = z2[(size_t)q3 * 64 + t];
          accx += (float)b0.x + m1 * (float)b1.x + m2 * (float)b2.x + m3 * (float)b3.x;
          accy += (float)b0.y + m1 * (float)b1.y + m2 * (float)b2.y + m3 * (float)b3.y;
        }
      }
    }
  }

  v2f o;
  o.x = fast_tanh(accx);
  o.y = fast_tanh(accy);
  ((v2f*)out)[(size_t)s * 64 + t] = o;
}

extern "C" void kernel_launch(void* const* d_in, const int* in_sizes, int n_in,
                              void* d_out, int out_size, void* d_ws, size_t ws_size,
                              hipStream_t stream) {
  const float* values = (const float*)d_in[0];   // [N_SRC, 128] f32
  const float* W      = (const float*)d_in[1];   // [128, 128] f32
  const int*   gidx   = (const int*)d_in[2];     // [E] int
  const int*   seg    = (const int*)d_in[3];     // [E] int, sorted
  float* out = (float*)d_out;                    // [N_OUT, 128] f32

  int*      offs = (int*)d_ws;                                        // [N_OUT+1]
  _Float16* Wt   = (_Float16*)((char*)d_ws + OFFS_BYTES);             // [128,128] fp16
  _Float16* z    = (_Float16*)((char*)d_ws + OFFS_BYTES + WT_BYTES);  // [N_SRC,128] fp16

  const int n_edges = in_sizes[2];

  build_offs<<<(n_edges + 255) / 256, 256, 0, stream>>>(seg, offs, n_edges, NUM_OUT);
  wt_fp16<<<(DIM * DIM + 255) / 256, 256, 0, stream>>>(W, Wt);
  transform_mfma<<<N_SRC / 64, 256, 0, stream>>>(values, Wt, z);
  seg_gather_tanh<<<NUM_OUT / 2, 128, 0, stream>>>(z, gidx, offs, out, n_edges);
}

// Round 14
// 137.933 us; speedup vs baseline: 1.3893x; 1.0001x over previous
//
#include <hip/hip_runtime.h>

#define DIM 128
#define NUM_OUT 100000
#define N_SRC 200000
#define OFFS_BYTES (((4 * (NUM_OUT + 1)) + 511) / 512 * 512)
#define WT_BYTES (DIM * DIM * 2)
#define ZT_STRIDE 136  // 16-row LDS out-tile stride in halfs (+8 pad)

typedef float v2f __attribute__((ext_vector_type(2)));
typedef float v4f __attribute__((ext_vector_type(4)));
typedef float f32x4 __attribute__((ext_vector_type(4)));
typedef _Float16 f16x2 __attribute__((ext_vector_type(2)));
typedef _Float16 f16x8 __attribute__((ext_vector_type(8)));

__device__ __forceinline__ float fast_tanh(float x) {
  const float xc = fminf(fmaxf(x, -15.f), 15.f);
  const float t = __expf(2.f * xc);
  return __fdividef(t - 1.f, t + 1.f);
}

// Kernel 0: segment boundaries. offs[s] = first edge e with seg[e] >= s.
__global__ __launch_bounds__(256) void build_offs(
    const int* __restrict__ seg, int* __restrict__ offs, int n_edges, int n_out) {
  const int e = blockIdx.x * 256 + threadIdx.x;
  if (e >= n_edges) return;
  const int se = seg[e];
  const int sp = (e == 0) ? -1 : seg[e - 1];
  for (int s = sp + 1; s <= se; ++s) offs[s] = e;
  if (e == n_edges - 1) {
    for (int s = se + 1; s <= n_out; ++s) offs[s] = n_edges;
  }
}

// Kernel 0b: Wt[n][k] = (fp16) W[k][n]. 16K elements, one-shot.
__global__ __launch_bounds__(256) void wt_fp16(
    const float* __restrict__ W, _Float16* __restrict__ Wt) {
  const int i = blockIdx.x * 256 + threadIdx.x;
  if (i >= DIM * DIM) return;
  const int k = i >> 7, n = i & 127;
  Wt[n * DIM + k] = (_Float16)W[i];
}

// Kernel 1: z = (fp16)(values @ W), f32 accum. 256 thr = 4 waves, 64 rows/blk.
// kb-outer / nt-inner: per kb, 8 INDEPENDENT Wt loads then 8 INDEPENDENT
// MFMAs (acc chains only 4 deep). Fully unrolled, static indexing. No
// barrier: zt tile is per-wave private. Fragment layout (R12-validated):
// A row=l&15, k at (l>>4)*8; B col=l&15; C/D col=l&15, row=(l>>4)*4+r.
__global__ __launch_bounds__(256, 4) void transform_mfma(
    const float* __restrict__ x,
    const _Float16* __restrict__ Wt,
    _Float16* __restrict__ z) {
  __shared__ _Float16 zt[4][16 * ZT_STRIDE];  // 17.4 KB

  const int tid = threadIdx.x;
  const int w = tid >> 6;
  const int l = tid & 63;
  const int m0 = blockIdx.x * 64 + w * 16;  // wave's 16 rows

  const int ar = l & 15;
  const int kblk = (l >> 4) * 8;

  f16x8 af[4];
#pragma unroll
  for (int kb = 0; kb < 4; ++kb) {
    const float* p = x + (size_t)(m0 + ar) * DIM + kb * 32 + kblk;
    const v4f x0 = *(const v4f*)(p);
    const v4f x1 = *(const v4f*)(p + 4);
    f16x8 h;
    h[0] = (_Float16)x0.x; h[1] = (_Float16)x0.y;
    h[2] = (_Float16)x0.z; h[3] = (_Float16)x0.w;
    h[4] = (_Float16)x1.x; h[5] = (_Float16)x1.y;
    h[6] = (_Float16)x1.z; h[7] = (_Float16)x1.w;
    af[kb] = h;
  }

  const int cr0 = (l >> 4) * 4;
  const int cc = l & 15;

  f32x4 acc[8];
#pragma unroll
  for (int nt = 0; nt < 8; ++nt) acc[nt] = (f32x4){0.f, 0.f, 0.f, 0.f};

#pragma unroll
  for (int kb = 0; kb < 4; ++kb) {
    f16x8 bf[8];
#pragma unroll
    for (int nt = 0; nt < 8; ++nt)
      bf[nt] = *(const f16x8*)(Wt + (size_t)(nt * 16 + cc) * DIM + kb * 32 + kblk);
#pragma unroll
    for (int nt = 0; nt < 8; ++nt)
      acc[nt] = __builtin_amdgcn_mfma_f32_16x16x32_f16(af[kb], bf[nt], acc[nt], 0, 0, 0);
  }

#pragma unroll
  for (int nt = 0; nt < 8; ++nt) {
#pragma unroll
    for (int r = 0; r < 4; ++r)
      zt[w][(cr0 + r) * ZT_STRIDE + nt * 16 + cc] = (_Float16)acc[nt][r];
  }

  // per-wave private tile: no barrier needed (lgkmcnt ordering within wave)

  // coalesced writeback: lane l -> row l>>2, chunks (l&3)+4j (8 halfs each)
  const int row = l >> 2;
#pragma unroll
  for (int j = 0; j < 4; ++j) {
    const int ch = (l & 3) + 4 * j;
    const f16x8 v = *(const f16x8*)(&zt[w][row * ZT_STRIDE + ch * 8]);
    *(f16x8*)(z + (size_t)(m0 + row) * DIM + ch * 8) = v;
  }
}

// Kernel 2: pure gather+segsum+tanh over fp16 z rows (256 B each).
// Bytes-wall limited (~7 TB/s delivered); proven form, do not touch.
__global__ __launch_bounds__(128) void seg_gather_tanh(
    const _Float16* __restrict__ zh,
    const int* __restrict__ gidx,
    const int* __restrict__ offs,
    float* __restrict__ out,
    int n_edges) {
  const int s = blockIdx.x * 2 + (threadIdx.x >> 6);
  const int t = threadIdx.x & 63;

  const int e0 = __builtin_amdgcn_readfirstlane(offs[s]);
  const int e1 = __builtin_amdgcn_readfirstlane(offs[s + 1]);
  const int len = e1 - e0;

  const f16x2* __restrict__ z2 = (const f16x2*)zh;
  float accx = 0.f, accy = 0.f;

  for (int base = 0; base < len; base += 64) {
    const int my = gidx[min(e0 + base + t, n_edges - 1)];
    const int n = min(64, len - base);
    int k = 0;
    for (; k + 8 <= n; k += 8) {
      int r0 = __builtin_amdgcn_readlane(my, k + 0);
      int r1 = __builtin_amdgcn_readlane(my, k + 1);
      int r2 = __builtin_amdgcn_readlane(my, k + 2);
      int r3 = __builtin_amdgcn_readlane(my, k + 3);
      int r4 = __builtin_amdgcn_readlane(my, k + 4);
      int r5 = __builtin_amdgcn_readlane(my, k + 5);
      int r6 = __builtin_amdgcn_readlane(my, k + 6);
      int r7 = __builtin_amdgcn_readlane(my, k + 7);
      const f16x2 a0 = z2[(size_t)r0 * 64 + t];
      const f16x2 a1 = z2[(size_t)r1 * 64 + t];
      const f16x2 a2 = z2[(size_t)r2 * 64 + t];
      const f16x2 a3 = z2[(size_t)r3 * 64 + t];
      const f16x2 a4 = z2[(size_t)r4 * 64 + t];
      const f16x2 a5 = z2[(size_t)r5 * 64 + t];
      const f16x2 a6 = z2[(size_t)r6 * 64 + t];
      const f16x2 a7 = z2[(size_t)r7 * 64 + t];
      accx += (float)a0.x + (float)a1.x + (float)a2.x + (float)a3.x +
              (float)a4.x + (float)a5.x + (float)a6.x + (float)a7.x;
      accy += (float)a0.y + (float)a1.y + (float)a2.y + (float)a3.y +
              (float)a4.y + (float)a5.y + (float)a6.y + (float)a7.y;
    }
    if (k < n) {
      const int nm1 = n - 1;
#pragma unroll
      for (int j = 0; j < 7; j += 4) {
        if (k + j < n) {
          int q0 = __builtin_amdgcn_readlane(my, min(k + j + 0, nm1));
          int q1 = __builtin_amdgcn_readlane(my, min(k + j + 1, nm1));
          int q2 = __builtin_amdgcn_readlane(my, min(k + j + 2, nm1));
          int q3 = __builtin_amdgcn_readlane(my, min(k + j + 3, nm1));
          const float m1 = (k + j + 1 < n) ? 1.f : 0.f;
          const float m2 = (k + j + 2 < n) ? 1.f : 0.f;
          const float m3 = (k + j + 3 < n) ? 1.f : 0.f;
          const f16x2 b0 = z2[(size_t)q0 * 64 + t];
          const f16x2 b1 = z2[(size_t)q1 * 64 + t];
          const f16x2 b2 = z2[(size_t)q2 * 64 + t];
          const f16x2 b3 = z2[(size_t)q3 * 64 + t];
          accx += (float)b0.x + m1 * (float)b1.x + m2 * (float)b2.x + m3 * (float)b3.x;
          accy += (float)b0.y + m1 * (float)b1.y + m2 * (float)b2.y + m3 * (float)b3.y;
        }
      }
    }
  }

  v2f o;
  o.x = fast_tanh(accx);
  o.y = fast_tanh(accy);
  ((v2f*)out)[(size_t)s * 64 + t] = o;
}

extern "C" void kernel_launch(void* const* d_in, const int* in_sizes, int n_in,
                              void* d_out, int out_size, void* d_ws, size_t ws_size,
                              hipStream_t stream) {
  const float* values = (const float*)d_in[0];   // [N_SRC, 128] f32
  const float* W      = (const float*)d_in[1];   // [128, 128] f32
  const int*   gidx   = (const int*)d_in[2];     // [E] int
  const int*   seg    = (const int*)d_in[3];     // [E] int, sorted
  float* out = (float*)d_out;                    // [N_OUT, 128] f32

  int*      offs = (int*)d_ws;                                        // [N_OUT+1]
  _Float16* Wt   = (_Float16*)((char*)d_ws + OFFS_BYTES);             // [128,128] fp16
  _Float16* z    = (_Float16*)((char*)d_ws + OFFS_BYTES + WT_BYTES);  // [N_SRC,128] fp16

  const int n_edges = in_sizes[2];

  wt_fp16<<<(DIM * DIM + 255) / 256, 256, 0, stream>>>(W, Wt);
  build_offs<<<(n_edges + 255) / 256, 256, 0, stream>>>(seg, offs, n_edges, NUM_OUT);
  transform_mfma<<<N_SRC / 64, 256, 0, stream>>>(values, Wt, z);
  seg_gather_tanh<<<NUM_OUT / 2, 128, 0, stream>>>(z, gidx, offs, out, n_edges);
}